// Round 18
// baseline (169.648 us; speedup 1.0000x reference)
//
#include <hip/hip_runtime.h>
#include <hip/hip_fp16.h>
#include <cstdint>

#define B_   4
#define S_   2048
#define HID_ 1024
#define NH_  16
#define HD_  64
#define M_   (B_ * S_)   // 8192

using f16   = _Float16;
using f16x4 = __attribute__((ext_vector_type(4))) _Float16;
using f16x8 = __attribute__((ext_vector_type(8))) _Float16;
using f32x4 = __attribute__((ext_vector_type(4))) float;
using u32x4 = __attribute__((ext_vector_type(4))) unsigned int;

// async 16B global -> LDS (HW writes wave-uniform base + lane*16)
__device__ __forceinline__ void g2lds16(const void* g, void* l) {
  __builtin_amdgcn_global_load_lds(
      (__attribute__((address_space(1))) void*)(uintptr_t)g,
      (__attribute__((address_space(3))) void*)(uint32_t)(uintptr_t)l,
      16, 0, 0);
}

// pack 2 f32 -> 2 f16 in one u32 (round-to-zero): src0 -> lo16, src1 -> hi16
__device__ __forceinline__ unsigned int pk16(float a, float b) {
  unsigned int r;
  asm("v_cvt_pkrtz_f16_f32 %0, %1, %2" : "=v"(r) : "v"(a), "v"(b));
  return r;
}

// key permutation for K-staging, 7-bit (128-key tiles; R6-validated 6-bit form):
// staged row [c2 c1 c0 g1 g0 r1 r0] -> true key [c2 c1 g1 g0 c0 r1 r0], so QK
// D-regs of 16-row tile cbt land on true keys (cbt>>1)*32 + g*8 + (cbt&1)*4 + r.
#define PIDX(r) (((r) & 96) | (((r) & 12) << 1) | ((((r) >> 4) & 1) << 2) | ((r) & 3))

#define CS_ 0.180336880111120426f  // 0.125 * log2(e)

// ---------------- fused f32 -> f16 convert (hs + Wq + Wk + Wv, one launch) --------
__global__ void cvt_all_k(const float* __restrict__ hs, const float* __restrict__ wq,
                          const float* __restrict__ wk, const float* __restrict__ wv,
                          f16* __restrict__ hsF, f16* __restrict__ wF) {
  const int bid = blockIdx.x, tid = threadIdx.x;
  const float* src;
  f16* dst;
  int i;
  if (bid < 8192) {                 // hs: 2M float4
    src = hs; dst = hsF; i = bid * 256 + tid;
  } else {                          // weights: 256K float4 each
    const int r = (bid - 8192) >> 10;
    src = (r == 0) ? wq : ((r == 1) ? wk : wv);
    dst = wF + (size_t)r * HID_ * HID_;
    i = ((bid - 8192) & 1023) * 256 + tid;
  }
  float4 v = ((const float4*)src)[i];
  f16x4 h;
  h[0] = (f16)v.x; h[1] = (f16)v.y; h[2] = (f16)v.z; h[3] = (f16)v.w;
  ((f16x4*)dst)[i] = h;
}

// ---------------- fused QKV projection GEMM (R14-validated) + XCD swizzle ---------
__global__ __launch_bounds__(256) void proj_gemm_k(
    const f16* __restrict__ A, const f16* __restrict__ W,
    const float* __restrict__ bq, const float* __restrict__ bk, const float* __restrict__ bv,
    f16* __restrict__ Out) {
  __shared__ __align__(16) f16 As[128 * 64];
  __shared__ __align__(16) f16 Bs[128 * 64];
  const int bid = blockIdx.x;
  const int swz = (bid & 7) * 192 + (bid >> 3);   // bijective: 1536 = 8*192
  const int bx = swz % 24, by = swz / 24;
  const int tid = threadIdx.x;
  const int l   = tid & 63;
  const int w   = tid >> 6;
  const int lr  = l & 15;
  const int lk  = (l >> 4) * 8;
  const int col0 = bx * 128;
  const int row0 = by * 128;
  const int wr = (w >> 1) * 64;
  const int wc = (w & 1) * 64;

  f32x4 acc[4][4] = {};

  for (int kt = 0; kt < 16; ++kt) {
    const int k0 = kt * 64;
#pragma unroll
    for (int i = 0; i < 4; ++i) {
      const int c   = tid + i * 256;
      const int row = c >> 3;
      const int cb  = (c ^ row) & 7;
      g2lds16(A + (size_t)(row0 + row) * 1024 + k0 + cb * 8,
              As + (w * 64 + i * 256) * 8);
      g2lds16(W + (size_t)(col0 + row) * 1024 + k0 + cb * 8,
              Bs + (w * 64 + i * 256) * 8);
    }
    asm volatile("s_waitcnt vmcnt(0)" ::: "memory");
    __syncthreads();

#pragma unroll
    for (int kk = 0; kk < 64; kk += 32) {
      const int x = (kk + lk) >> 3;
      f16x8 af[4], bf[4];
#pragma unroll
      for (int m = 0; m < 4; ++m) {
        const int row = wr + m * 16 + lr;
        af[m] = *(const f16x8*)(As + (row * 8 + ((x ^ row) & 7)) * 8);
      }
#pragma unroll
      for (int n = 0; n < 4; ++n) {
        const int row = wc + n * 16 + lr;
        bf[n] = *(const f16x8*)(Bs + (row * 8 + ((x ^ row) & 7)) * 8);
      }
#pragma unroll
      for (int m = 0; m < 4; ++m)
#pragma unroll
        for (int n = 0; n < 4; ++n)
          acc[m][n] = __builtin_amdgcn_mfma_f32_16x16x32_f16(af[m], bf[n], acc[m][n], 0, 0, 0);
    }
    __syncthreads();
  }

  const int proj = col0 >> 10;
  const float* bias = (proj == 0) ? bq : ((proj == 1) ? bk : bv);
  f16* outp = Out + (size_t)proj * ((size_t)M_ * HID_);
#pragma unroll
  for (int n = 0; n < 4; ++n) {
    const int col = col0 + wc + n * 16 + lr;
    const int cp  = col & 1023;
    const float bb = bias[cp];
#pragma unroll
    for (int m = 0; m < 4; ++m) {
      const int rbase = row0 + wr + m * 16 + (l >> 4) * 4;
#pragma unroll
      for (int r = 0; r < 4; ++r)
        outp[(size_t)(rbase + r) * 1024 + cp] = (f16)(acc[m][n][r] + bb);
    }
  }
}

// ---------------- keff + V-transpose prep (R14-validated) ----------------
// keff_s = CS_ * (k/8 + softsign(softsign(k)/8) + v)
__global__ __launch_bounds__(256) void prep_kv_k(
    const f16* __restrict__ Kp, const f16* __restrict__ Vp,
    f16* __restrict__ Keff, f16* __restrict__ Vt) {
  const int bh = blockIdx.x;  // 64
  const int st = blockIdx.y;  // 32
  const int b = bh >> 4, h = bh & 15;
  const int tid = threadIdx.x;
#pragma unroll
  for (int i = 0; i < 2; ++i) {
    const int c  = tid + i * 256;
    const int sl = c >> 3, cb = c & 7;
    const int s  = st * 64 + sl;
    const size_t src = (size_t)(b * S_ + s) * 1024 + h * 64 + cb * 8;
    const f16x8 kv = *(const f16x8*)(Kp + src);
    const f16x8 vv = *(const f16x8*)(Vp + src);
    f16x8 ke;
#pragma unroll
    for (int j = 0; j < 8; ++j) {
      const float kf = (float)kv[j], vf = (float)vv[j];
      const float s1 = kf / (1.f + fabsf(kf));
      const float t  = s1 * 0.125f;
      const float s2 = t / (1.f + fabsf(t));
      ke[j] = (f16)((kf * 0.125f + s2 + vf) * CS_);
    }
    *(f16x8*)(Keff + ((size_t)bh * S_ + s) * 64 + cb * 8) = ke;
#pragma unroll
    for (int j = 0; j < 8; ++j)
      Vt[((size_t)bh * 64 + cb * 8 + j) * S_ + s] = vv[j];
  }
}

// ---------------- flash attention: KVBLK=128 (half the barriers), qb=2 ------------
// block = (bh, qtile of 256 rows), 8 waves x 32 q; K/V tiles 128 keys, dbuf.
// All fragment mappings = R16-validated family; PIDX extended to 7 bits.
// 16 outer iterations (was 32) -> vmcnt(0)+barrier overhead halved.
__global__ __launch_bounds__(512) void attn_k(
    const f16* __restrict__ Q,     // [8192][1024]
    const f16* __restrict__ Keff,  // [64][2048][64]  (pre-scaled by CS_)
    const f16* __restrict__ Vt,    // [64][64][2048]
    const int* __restrict__ mask,  // [4][2048]
    float* __restrict__ Out) {     // [8192][1024] f32
  __shared__ __align__(16) f16 Kl[2][128 * 64];   // [staged key row][d]   16KB x2
  __shared__ __align__(16) f16 Vl[2][64 * 128];   // [d][key]              16KB x2
  const int bh = blockIdx.x, qt = blockIdx.y;     // qt 0..7
  const int b = bh >> 4, h = bh & 15;
  const int tid = threadIdx.x;
  const int l = tid & 63, w = tid >> 6;   // w in 0..7
  const int lr = l & 15, g = l >> 4;

  // Q fragments (B-operand of mfma(kf,qf)); zeroed if q-row masked.
  f16x8 qf[2][2];
#pragma unroll
  for (int qb = 0; qb < 2; ++qb) {
    const int qrow = qt * 256 + w * 32 + qb * 16 + lr;
    const f16* qs = Q + (size_t)(b * S_ + qrow) * 1024 + h * 64 + g * 8;
    qf[qb][0] = *(const f16x8*)(qs);
    qf[qb][1] = *(const f16x8*)(qs + 32);
    if (mask[b * S_ + qrow] == 0) {
      qf[qb][0] = (f16x8)(f16)0;
      qf[qb][1] = (f16x8)(f16)0;
    }
  }

  // staging GLOBAL pointers: per thread 2 K-chunks + 2 V-chunks (1024 each/tile).
  // K: chunk n -> staged row n>>3 (PIDX-permuted source), chunk (n&7)^(row&7).
  // V: chunk n -> d-row n>>4, chunk (n&15)^(row&15) of the 16 key-chunks.
  const f16* kg[2];
  const f16* vg[2];
#pragma unroll
  for (int i = 0; i < 2; ++i) {
    const int n = tid + i * 512;
    const int krow = n >> 3, kc = (n & 7) ^ (krow & 7);
    kg[i] = Keff + ((size_t)bh * S_ + PIDX(krow)) * 64 + kc * 8;
    const int vrow = n >> 4, vc = (n & 15) ^ (vrow & 15);
    vg[i] = Vt + ((size_t)bh * 64 + vrow) * 2048 + vc * 8;
  }

  f32x4 ctx[2][4] = {};    // ctx[qb][db][r] = O[q=lr][d=db*16+g*4+r]
  float lacc[2] = {0.f, 0.f};   // scalar row-sum (R16-validated; lacc4 regressed)

#define STAGE(bf, t)                                                           \
  {                                                                            \
    _Pragma("unroll") for (int i = 0; i < 2; ++i) {                            \
      g2lds16(kg[i] + (size_t)(t) * 8192, &Kl[bf][(i * 512 + w * 64) * 8]);    \
      g2lds16(vg[i] + (size_t)(t) * 128, &Vl[bf][(i * 512 + w * 64) * 8]);     \
    }                                                                          \
  }

  STAGE(0, 0);
  asm volatile("s_waitcnt vmcnt(0)" ::: "memory");
  __syncthreads();

  for (int kt = 0; kt < 16; ++kt) {
    const int cur = kt & 1;
    if (kt < 15) STAGE(cur ^ 1, kt + 1);

    // ---- QK + softmax-lite: 4 cbp slices of 2 cc-tiles (32 keys each) ----
    f16x8 pf[2][4];   // pf[qb][cbp]: P[q=lr][true keys cbp*32 + g*8 .. +7]
#pragma unroll
    for (int cbp = 0; cbp < 4; ++cbp) {
      f32x4 sv[2][2] = {};
      __builtin_amdgcn_s_setprio(1);
#pragma unroll
      for (int kk = 0; kk < 2; ++kk)
#pragma unroll
        for (int cc = 0; cc < 2; ++cc) {
          const int row = (cbp * 2 + cc) * 16 + lr;
          const f16x8 kf = *(const f16x8*)(&Kl[cur][(row * 8 + ((kk * 4 + g) ^ (row & 7))) * 8]);
#pragma unroll
          for (int qb = 0; qb < 2; ++qb)
            sv[qb][cc] = __builtin_amdgcn_mfma_f32_16x16x32_f16(kf, qf[qb][kk], sv[qb][cc], 0, 0, 0);
        }
      __builtin_amdgcn_s_setprio(0);
#pragma unroll
      for (int qb = 0; qb < 2; ++qb) {
        float pv[2][4];
        float s = 0.f;
#pragma unroll
        for (int cc = 0; cc < 2; ++cc)
#pragma unroll
          for (int r = 0; r < 4; ++r) {
            const float pe = __builtin_amdgcn_exp2f(sv[qb][cc][r]);  // raw v_exp_f32
            pv[cc][r] = pe;
            s += pe;
          }
        lacc[qb] += s;
        u32x4 pw = {pk16(pv[0][0], pv[0][1]), pk16(pv[0][2], pv[0][3]),
                    pk16(pv[1][0], pv[1][1]), pk16(pv[1][2], pv[1][3])};
        pf[qb][cbp] = __builtin_bit_cast(f16x8, pw);
      }
    }

    // ---- PV: contract 128 keys = 4 kkp fragments; mfma(vf, pf) ----
    __builtin_amdgcn_s_setprio(1);
#pragma unroll
    for (int kkp = 0; kkp < 4; ++kkp)
#pragma unroll
      for (int db = 0; db < 4; ++db) {
        const int row = db * 16 + lr;
        const f16x8 vf = *(const f16x8*)(&Vl[cur][(row * 16 + ((kkp * 4 + g) ^ (row & 15))) * 8]);
#pragma unroll
        for (int qb = 0; qb < 2; ++qb)
          ctx[qb][db] = __builtin_amdgcn_mfma_f32_16x16x32_f16(vf, pf[qb][kkp], ctx[qb][db], 0, 0, 0);
      }
    __builtin_amdgcn_s_setprio(0);

    asm volatile("s_waitcnt vmcnt(0)" ::: "memory");
    __syncthreads();
  }

  // ---- finalize: cross-group sum (shfl), divide, store f32x4 ----
#pragma unroll
  for (int qb = 0; qb < 2; ++qb) {
    float ls = lacc[qb];
    ls += __shfl_xor(ls, 16);
    ls += __shfl_xor(ls, 32);
    const float linv = 1.0f / ls;
    const int qrow = qt * 256 + w * 32 + qb * 16 + lr;
    float* op = Out + (size_t)(b * S_ + qrow) * 1024 + h * 64 + g * 4;
#pragma unroll
    for (int db = 0; db < 4; ++db) {
      f32x4 o = ctx[qb][db] * linv;
      *(f32x4*)(op + db * 16) = o;
    }
  }
}

extern "C" void kernel_launch(void* const* d_in, const int* in_sizes, int n_in,
                              void* d_out, int out_size, void* d_ws, size_t ws_size,
                              hipStream_t stream) {
  const float* hs = (const float*)d_in[0];
  const float* Wq = (const float*)d_in[1];
  const float* bq = (const float*)d_in[2];
  const float* Wk = (const float*)d_in[3];
  const float* bk = (const float*)d_in[4];
  const float* Wv = (const float*)d_in[5];
  const float* bv = (const float*)d_in[6];
  const int* mask = (const int*)d_in[7];
  float* out = (float*)d_out;

  f16* hsF  = (f16*)d_ws;                       // 8192*1024
  f16* wF   = hsF + (size_t)M_ * HID_;          // 3*1024*1024 (Wq, Wk, Wv)
  f16* qF   = wF + 3ull * HID_ * HID_;          // 8192*1024
  f16* kF   = qF + (size_t)M_ * HID_;           // 8192*1024
  f16* vF   = kF + (size_t)M_ * HID_;           // 8192*1024
  f16* keff = vF + (size_t)M_ * HID_;           // 64*2048*64
  f16* vt   = keff + (size_t)M_ * HID_;         // 64*64*2048

  cvt_all_k<<<dim3(8192 + 3072), 256, 0, stream>>>(hs, Wq, Wk, Wv, hsF, wF);
  proj_gemm_k<<<dim3(1536), 256, 0, stream>>>(hsF, wF, bq, bk, bv, qF);
  prep_kv_k<<<dim3(64, 32), 256, 0, stream>>>(kF, vF, keff, vt);
  attn_k<<<dim3(64, 8), 512, 0, stream>>>(qF, keff, vt, mask, out);
}

// Round 19
// 164.572 us; speedup vs baseline: 1.0308x; 1.0308x over previous
//
#include <hip/hip_runtime.h>
#include <hip/hip_fp16.h>
#include <cstdint>

#define B_   4
#define S_   2048
#define HID_ 1024
#define NH_  16
#define HD_  64
#define M_   (B_ * S_)   // 8192

using f16   = _Float16;
using f16x4 = __attribute__((ext_vector_type(4))) _Float16;
using f16x8 = __attribute__((ext_vector_type(8))) _Float16;
using f32x4 = __attribute__((ext_vector_type(4))) float;
using u32x4 = __attribute__((ext_vector_type(4))) unsigned int;

// async 16B global -> LDS (HW writes wave-uniform base + lane*16)
__device__ __forceinline__ void g2lds16(const void* g, void* l) {
  __builtin_amdgcn_global_load_lds(
      (__attribute__((address_space(1))) void*)(uintptr_t)g,
      (__attribute__((address_space(3))) void*)(uint32_t)(uintptr_t)l,
      16, 0, 0);
}

// pack 2 f32 -> 2 f16 in one u32 (round-to-zero): src0 -> lo16, src1 -> hi16
__device__ __forceinline__ unsigned int pk16(float a, float b) {
  unsigned int r;
  asm("v_cvt_pkrtz_f16_f32 %0, %1, %2" : "=v"(r) : "v"(a), "v"(b));
  return r;
}

// key permutation for K-staging (R6-validated): staged row -> true key bit-shuffle
// [c1 c0 g1 g0 r1 r0] -> [c1 g1 g0 c0 r1 r0]; QK D-regs land on keys kk*32+g*8+..
#define PIDX(r) (((r) & 32) | (((r) & 12) << 1) | ((((r) >> 4) & 1) << 2) | ((r) & 3))

#define CS_ 0.180336880111120426f  // 0.125 * log2(e)

// ---------------- fused f32 -> f16 convert (hs + Wq + Wk + Wv, one launch) --------
__global__ void cvt_all_k(const float* __restrict__ hs, const float* __restrict__ wq,
                          const float* __restrict__ wk, const float* __restrict__ wv,
                          f16* __restrict__ hsF, f16* __restrict__ wF) {
  const int bid = blockIdx.x, tid = threadIdx.x;
  const float* src;
  f16* dst;
  int i;
  if (bid < 8192) {                 // hs: 2M float4
    src = hs; dst = hsF; i = bid * 256 + tid;
  } else {                          // weights: 256K float4 each
    const int r = (bid - 8192) >> 10;
    src = (r == 0) ? wq : ((r == 1) ? wk : wv);
    dst = wF + (size_t)r * HID_ * HID_;
    i = ((bid - 8192) & 1023) * 256 + tid;
  }
  float4 v = ((const float4*)src)[i];
  f16x4 h;
  h[0] = (f16)v.x; h[1] = (f16)v.y; h[2] = (f16)v.z; h[3] = (f16)v.w;
  ((f16x4*)dst)[i] = h;
}

// ---------------- fused QKV projection GEMM (R14-validated) ----------------
__global__ __launch_bounds__(256) void proj_gemm_k(
    const f16* __restrict__ A, const f16* __restrict__ W,
    const float* __restrict__ bq, const float* __restrict__ bk, const float* __restrict__ bv,
    f16* __restrict__ Out) {
  __shared__ __align__(16) f16 As[128 * 64];
  __shared__ __align__(16) f16 Bs[128 * 64];
  const int tid = threadIdx.x;
  const int l   = tid & 63;
  const int w   = tid >> 6;
  const int lr  = l & 15;
  const int lk  = (l >> 4) * 8;
  const int col0 = blockIdx.x * 128;
  const int row0 = blockIdx.y * 128;
  const int wr = (w >> 1) * 64;
  const int wc = (w & 1) * 64;

  f32x4 acc[4][4] = {};

  for (int kt = 0; kt < 16; ++kt) {
    const int k0 = kt * 64;
#pragma unroll
    for (int i = 0; i < 4; ++i) {
      const int c   = tid + i * 256;
      const int row = c >> 3;
      const int cb  = (c ^ row) & 7;
      g2lds16(A + (size_t)(row0 + row) * 1024 + k0 + cb * 8,
              As + (w * 64 + i * 256) * 8);
      g2lds16(W + (size_t)(col0 + row) * 1024 + k0 + cb * 8,
              Bs + (w * 64 + i * 256) * 8);
    }
    asm volatile("s_waitcnt vmcnt(0)" ::: "memory");
    __syncthreads();

#pragma unroll
    for (int kk = 0; kk < 64; kk += 32) {
      const int x = (kk + lk) >> 3;
      f16x8 af[4], bf[4];
#pragma unroll
      for (int m = 0; m < 4; ++m) {
        const int row = wr + m * 16 + lr;
        af[m] = *(const f16x8*)(As + (row * 8 + ((x ^ row) & 7)) * 8);
      }
#pragma unroll
      for (int n = 0; n < 4; ++n) {
        const int row = wc + n * 16 + lr;
        bf[n] = *(const f16x8*)(Bs + (row * 8 + ((x ^ row) & 7)) * 8);
      }
#pragma unroll
      for (int m = 0; m < 4; ++m)
#pragma unroll
        for (int n = 0; n < 4; ++n)
          acc[m][n] = __builtin_amdgcn_mfma_f32_16x16x32_f16(af[m], bf[n], acc[m][n], 0, 0, 0);
    }
    __syncthreads();
  }

  const int proj = col0 >> 10;
  const float* bias = (proj == 0) ? bq : ((proj == 1) ? bk : bv);
  f16* outp = Out + (size_t)proj * ((size_t)M_ * HID_);
#pragma unroll
  for (int n = 0; n < 4; ++n) {
    const int col = col0 + wc + n * 16 + lr;
    const int cp  = col & 1023;
    const float bb = bias[cp];
#pragma unroll
    for (int m = 0; m < 4; ++m) {
      const int rbase = row0 + wr + m * 16 + (l >> 4) * 4;
#pragma unroll
      for (int r = 0; r < 4; ++r)
        outp[(size_t)(rbase + r) * 1024 + cp] = (f16)(acc[m][n][r] + bb);
    }
  }
}

// ---------------- keff + V-transpose prep (R14-validated) ----------------
// keff_s = CS_ * (k/8 + softsign(softsign(k)/8) + v)
__global__ __launch_bounds__(256) void prep_kv_k(
    const f16* __restrict__ Kp, const f16* __restrict__ Vp,
    f16* __restrict__ Keff, f16* __restrict__ Vt) {
  const int bh = blockIdx.x;  // 64
  const int st = blockIdx.y;  // 32
  const int b = bh >> 4, h = bh & 15;
  const int tid = threadIdx.x;
#pragma unroll
  for (int i = 0; i < 2; ++i) {
    const int c  = tid + i * 256;
    const int sl = c >> 3, cb = c & 7;
    const int s  = st * 64 + sl;
    const size_t src = (size_t)(b * S_ + s) * 1024 + h * 64 + cb * 8;
    const f16x8 kv = *(const f16x8*)(Kp + src);
    const f16x8 vv = *(const f16x8*)(Vp + src);
    f16x8 ke;
#pragma unroll
    for (int j = 0; j < 8; ++j) {
      const float kf = (float)kv[j], vf = (float)vv[j];
      const float s1 = kf / (1.f + fabsf(kf));
      const float t  = s1 * 0.125f;
      const float s2 = t / (1.f + fabsf(t));
      ke[j] = (f16)((kf * 0.125f + s2 + vf) * CS_);
    }
    *(f16x8*)(Keff + ((size_t)bh * S_ + s) * 64 + cb * 8) = ke;
#pragma unroll
    for (int j = 0; j < 8; ++j)
      Vt[((size_t)bh * 64 + cb * 8 + j) * S_ + s] = vv[j];
  }
}

// ---------------- flash attention (R15/R16-validated): qb=2, 2 blocks/CU ----------
__global__ __launch_bounds__(512) void attn_k(
    const f16* __restrict__ Q,     // [8192][1024]
    const f16* __restrict__ Keff,  // [64][2048][64]  (pre-scaled by CS_)
    const f16* __restrict__ Vt,    // [64][64][2048]
    const int* __restrict__ mask,  // [4][2048]
    float* __restrict__ Out) {     // [8192][1024] f32
  __shared__ __align__(16) f16 Kl[2][64 * 64];
  __shared__ __align__(16) f16 Vl[2][64 * 64];
  const int bh = blockIdx.x, qt = blockIdx.y;   // qt 0..7
  const int b = bh >> 4, h = bh & 15;
  const int tid = threadIdx.x;
  const int l = tid & 63, w = tid >> 6;   // w in 0..7
  const int lr = l & 15, g = l >> 4;

  // Q fragments (B-operand of mfma(kf,qf)); zeroed if q-row masked.
  f16x8 qf[2][2];
#pragma unroll
  for (int qb = 0; qb < 2; ++qb) {
    const int qrow = qt * 256 + w * 32 + qb * 16 + lr;
    const f16* qs = Q + (size_t)(b * S_ + qrow) * 1024 + h * 64 + g * 8;
    qf[qb][0] = *(const f16x8*)(qs);
    qf[qb][1] = *(const f16x8*)(qs + 32);
    if (mask[b * S_ + qrow] == 0) {
      qf[qb][0] = (f16x8)(f16)0;
      qf[qb][1] = (f16x8)(f16)0;
    }
  }

  // staging GLOBAL pointers (one K chunk + one V chunk per thread; 512 chunks each)
  const int srow = tid >> 3, scl = tid & 7;
  const int sc = scl ^ (srow & 7);
  const f16* kg = Keff + ((size_t)bh * S_ + PIDX(srow)) * 64 + sc * 8;
  const f16* vg = Vt + ((size_t)bh * 64 + srow) * 2048 + sc * 8;

  f32x4 ctx[2][4] = {};    // ctx[qb][db][r] = O[q=lr][d=db*16+g*4+r]
  float lacc[2] = {0.f, 0.f};

#define STAGE(bf, t)                                                           \
  {                                                                            \
    g2lds16(kg + (size_t)(t) * 4096, &Kl[bf][(w * 64) * 8]);                   \
    g2lds16(vg + (size_t)(t) * 64, &Vl[bf][(w * 64) * 8]);                     \
  }

  STAGE(0, 0);
  asm volatile("s_waitcnt vmcnt(0)" ::: "memory");
  __syncthreads();

  for (int kt = 0; kt < 32; ++kt) {
    const int cur = kt & 1;
    if (kt < 31) STAGE(cur ^ 1, kt + 1);

    // ---- QK + softmax-lite, in cb-pair slices (validated) ----
    f16x8 pf[2][2];   // pf[qb][cbp]: P[q=lr][true keys cbp*32 + g*8 .. +7]
#pragma unroll
    for (int cbp = 0; cbp < 2; ++cbp) {
      f32x4 sv[2][2] = {};
      __builtin_amdgcn_s_setprio(1);
#pragma unroll
      for (int kk = 0; kk < 2; ++kk)
#pragma unroll
        for (int cc = 0; cc < 2; ++cc) {
          const int row = (cbp * 2 + cc) * 16 + lr;
          const f16x8 kf = *(const f16x8*)(&Kl[cur][(row * 8 + ((kk * 4 + g) ^ (row & 7))) * 8]);
#pragma unroll
          for (int qb = 0; qb < 2; ++qb)
            sv[qb][cc] = __builtin_amdgcn_mfma_f32_16x16x32_f16(kf, qf[qb][kk], sv[qb][cc], 0, 0, 0);
        }
      __builtin_amdgcn_s_setprio(0);
#pragma unroll
      for (int qb = 0; qb < 2; ++qb) {
        float pv[2][4];
        float s = 0.f;
#pragma unroll
        for (int cc = 0; cc < 2; ++cc)
#pragma unroll
          for (int r = 0; r < 4; ++r) {
            const float pe = __builtin_amdgcn_exp2f(sv[qb][cc][r]);  // raw v_exp_f32
            pv[cc][r] = pe;
            s += pe;
          }
        lacc[qb] += s;
        u32x4 pw = {pk16(pv[0][0], pv[0][1]), pk16(pv[0][2], pv[0][3]),
                    pk16(pv[1][0], pv[1][1]), pk16(pv[1][2], pv[1][3])};
        pf[qb][cbp] = __builtin_bit_cast(f16x8, pw);
      }
    }

    // ---- PV: mfma(vf, pf) ----
    __builtin_amdgcn_s_setprio(1);
#pragma unroll
    for (int kk = 0; kk < 2; ++kk)
#pragma unroll
      for (int db = 0; db < 4; ++db) {
        const int row = db * 16 + lr;
        const f16x8 vf = *(const f16x8*)(&Vl[cur][(row * 8 + ((kk * 4 + g) ^ (row & 7))) * 8]);
#pragma unroll
        for (int qb = 0; qb < 2; ++qb)
          ctx[qb][db] = __builtin_amdgcn_mfma_f32_16x16x32_f16(vf, pf[qb][kk], ctx[qb][db], 0, 0, 0);
      }
    __builtin_amdgcn_s_setprio(0);

    asm volatile("s_waitcnt vmcnt(0)" ::: "memory");
    __syncthreads();
  }

  // ---- finalize: cross-group sum (shfl), divide, store f32x4 ----
#pragma unroll
  for (int qb = 0; qb < 2; ++qb) {
    float ls = lacc[qb];
    ls += __shfl_xor(ls, 16);
    ls += __shfl_xor(ls, 32);
    const float linv = 1.0f / ls;
    const int qrow = qt * 256 + w * 32 + qb * 16 + lr;
    float* op = Out + (size_t)(b * S_ + qrow) * 1024 + h * 64 + g * 4;
#pragma unroll
    for (int db = 0; db < 4; ++db) {
      f32x4 o = ctx[qb][db] * linv;
      *(f32x4*)(op + db * 16) = o;
    }
  }
}

extern "C" void kernel_launch(void* const* d_in, const int* in_sizes, int n_in,
                              void* d_out, int out_size, void* d_ws, size_t ws_size,
                              hipStream_t stream) {
  const float* hs = (const float*)d_in[0];
  const float* Wq = (const float*)d_in[1];
  const float* bq = (const float*)d_in[2];
  const float* Wk = (const float*)d_in[3];
  const float* bk = (const float*)d_in[4];
  const float* Wv = (const float*)d_in[5];
  const float* bv = (const float*)d_in[6];
  const int* mask = (const int*)d_in[7];
  float* out = (float*)d_out;

  f16* hsF  = (f16*)d_ws;                       // 8192*1024
  f16* wF   = hsF + (size_t)M_ * HID_;          // 3*1024*1024 (Wq, Wk, Wv)
  f16* qF   = wF + 3ull * HID_ * HID_;          // 8192*1024
  f16* kF   = qF + (size_t)M_ * HID_;           // 8192*1024
  f16* vF   = kF + (size_t)M_ * HID_;           // 8192*1024
  f16* keff = vF + (size_t)M_ * HID_;           // 64*2048*64
  f16* vt   = keff + (size_t)M_ * HID_;         // 64*64*2048

  cvt_all_k<<<dim3(8192 + 3072), 256, 0, stream>>>(hs, Wq, Wk, Wv, hsF, wF);
  proj_gemm_k<<<dim3(24, 64), 256, 0, stream>>>(hsF, wF, bq, bk, bv, qF);
  prep_kv_k<<<dim3(64, 32), 256, 0, stream>>>(kF, vF, keff, vt);
  attn_k<<<dim3(64, 8), 512, 0, stream>>>(qF, keff, vt, mask, out);
}